// Round 4
// baseline (529.493 us; speedup 1.0000x reference)
//
#include <hip/hip_runtime.h>
#include <hip/hip_fp16.h>

#define HD 128   // hidden dim

// ---- 4-replica degree counting: 4 edges/thread via int4, 8 atomics in flight ----
__global__ __launch_bounds__(256) void count_deg4(const int* __restrict__ src,
                                                  const int* __restrict__ dst,
                                                  unsigned int* __restrict__ cnt4s,
                                                  unsigned int* __restrict__ cnt4d,
                                                  int N, int E) {
    int t = blockIdx.x * 256 + threadIdx.x;
    int e0 = t * 4;
    if (e0 >= E) return;
    if (e0 + 3 < E) {
        int4 s4 = ((const int4*)src)[t];
        int4 d4 = ((const int4*)dst)[t];
        atomicAdd(&cnt4s[0 * N + s4.x], 1u);
        atomicAdd(&cnt4s[1 * N + s4.y], 1u);
        atomicAdd(&cnt4s[2 * N + s4.z], 1u);
        atomicAdd(&cnt4s[3 * N + s4.w], 1u);
        atomicAdd(&cnt4d[0 * N + d4.x], 1u);
        atomicAdd(&cnt4d[1 * N + d4.y], 1u);
        atomicAdd(&cnt4d[2 * N + d4.z], 1u);
        atomicAdd(&cnt4d[3 * N + d4.w], 1u);
    } else {
        for (int j = 0; e0 + j < E; ++j) {
            atomicAdd(&cnt4s[j * N + src[e0 + j]], 1u);
            atomicAdd(&cnt4d[j * N + dst[e0 + j]], 1u);
        }
    }
}

// ---- norms from replica sums; total in-degree cnt for aggregate/scan ----
__global__ __launch_bounds__(256) void make_norms(const unsigned int* __restrict__ cnt4s,
                                                  const unsigned int* __restrict__ cnt4d,
                                                  float* __restrict__ norm_src,
                                                  float* __restrict__ norm_dst,
                                                  unsigned int* __restrict__ cnt, int N) {
    int i = blockIdx.x * 256 + threadIdx.x;
    if (i < N) {
        unsigned int od = cnt4s[i] + cnt4s[N + i] + cnt4s[2 * N + i] + cnt4s[3 * N + i];
        unsigned int id = cnt4d[i] + cnt4d[N + i] + cnt4d[2 * N + i] + cnt4d[3 * N + i];
        cnt[i] = id;
        float odf = (float)od, idf = (float)id;
        norm_src[i] = rsqrtf(odf > 1.0f ? odf : 1.0f);
        norm_dst[i] = rsqrtf(idf > 1.0f ? idf : 1.0f);
    }
}

// ---- exclusive scan of cnt -> offsets (3 phases) ----
__global__ __launch_bounds__(256) void scan_a(const unsigned int* __restrict__ cnt,
                                              unsigned int* __restrict__ excl,
                                              unsigned int* __restrict__ bsum, int n) {
    int i = blockIdx.x * 256 + threadIdx.x;
    unsigned int v = (i < n) ? cnt[i] : 0u;
    unsigned int x = v;
#pragma unroll
    for (int d = 1; d < 64; d <<= 1) {
        unsigned int y = __shfl_up(x, d, 64);
        if ((threadIdx.x & 63) >= d) x += y;
    }
    __shared__ unsigned int wsum[4];
    if ((threadIdx.x & 63) == 63) wsum[threadIdx.x >> 6] = x;
    __syncthreads();
    unsigned int woff = 0;
    for (int w = 0; w < (int)(threadIdx.x >> 6); ++w) woff += wsum[w];
    unsigned int incl = x + woff;
    if (i < n) excl[i] = incl - v;
    if (threadIdx.x == 255) bsum[blockIdx.x] = incl;
}

__global__ __launch_bounds__(1024) void scan_b(const unsigned int* __restrict__ bsum,
                                               unsigned int* __restrict__ boff, int nb) {
    int t = threadIdx.x;
    unsigned int v = (t < nb) ? bsum[t] : 0u;
    unsigned int x = v;
#pragma unroll
    for (int d = 1; d < 64; d <<= 1) {
        unsigned int y = __shfl_up(x, d, 64);
        if ((t & 63) >= d) x += y;
    }
    __shared__ unsigned int wsum[16];
    if ((t & 63) == 63) wsum[t >> 6] = x;
    __syncthreads();
    unsigned int woff = 0;
    for (int w = 0; w < (t >> 6); ++w) woff += wsum[w];
    unsigned int incl = x + woff;
    if (t < nb) boff[t] = incl - v;
}

// finalize offsets AND init per-replica cursors to their segment bases
__global__ __launch_bounds__(256) void scan_c_base(unsigned int* __restrict__ excl,
                                                   const unsigned int* __restrict__ boff,
                                                   const unsigned int* __restrict__ cnt4d,
                                                   unsigned int* __restrict__ cur4, int N) {
    int i = blockIdx.x * 256 + threadIdx.x;
    if (i < N) {
        unsigned int o = excl[i] + boff[blockIdx.x];
        excl[i] = o;
        unsigned int c0 = cnt4d[i], c1 = cnt4d[N + i], c2 = cnt4d[2 * N + i];
        cur4[i]         = o;
        cur4[N + i]     = o + c0;
        cur4[2 * N + i] = o + c0 + c1;
        cur4[3 * N + i] = o + c0 + c1 + c2;
    }
}

// ---- scatter edge src-ids into dst-sorted order, 4-replica cursors ----
__global__ __launch_bounds__(256) void fill_csr4(const int* __restrict__ src,
                                                 const int* __restrict__ dst,
                                                 unsigned int* __restrict__ cur4,
                                                 int* __restrict__ sorted_src,
                                                 int N, int E) {
    int t = blockIdx.x * 256 + threadIdx.x;
    int e0 = t * 4;
    if (e0 >= E) return;
    if (e0 + 3 < E) {
        int4 s4 = ((const int4*)src)[t];
        int4 d4 = ((const int4*)dst)[t];
        unsigned int p0 = atomicAdd(&cur4[0 * N + d4.x], 1u);
        unsigned int p1 = atomicAdd(&cur4[1 * N + d4.y], 1u);
        unsigned int p2 = atomicAdd(&cur4[2 * N + d4.z], 1u);
        unsigned int p3 = atomicAdd(&cur4[3 * N + d4.w], 1u);
        sorted_src[p0] = s4.x;
        sorted_src[p1] = s4.y;
        sorted_src[p2] = s4.z;
        sorted_src[p3] = s4.w;
    } else {
        for (int j = 0; e0 + j < E; ++j) {
            unsigned int p = atomicAdd(&cur4[j * N + dst[e0 + j]], 1u);
            sorted_src[p] = src[e0 + j];
        }
    }
}

// ---- h = (x * norm_src[:,None]) @ W, fp16 output ----
__global__ __launch_bounds__(256) void gemm_norm(const float* __restrict__ x,
                                                 const float* __restrict__ norm,
                                                 const float* __restrict__ W,
                                                 __half* __restrict__ h, int n) {
    __shared__ float Ws[HD * HD];     // 64 KB
    __shared__ float xs[32][HD];      // 16 KB
    const float4* W4 = (const float4*)W;
    float4* Ws4 = (float4*)Ws;
#pragma unroll
    for (int i = 0; i < 16; ++i)
        Ws4[threadIdx.x + 256 * i] = W4[threadIdx.x + 256 * i];

    const int tid  = threadIdx.x;
    const int row0 = blockIdx.x * 32;

    {
        int r  = tid >> 3;
        int c0 = (tid & 7) * 4;
        int row = row0 + r;
        float nrm = (row < n) ? norm[row] : 0.f;
        const float4* xr = (const float4*)(x + (size_t)row * HD);
        float4* xd = (float4*)xs[r];
#pragma unroll
        for (int j = 0; j < 4; ++j) {
            float4 v = (row < n) ? xr[c0 + j] : make_float4(0.f, 0.f, 0.f, 0.f);
            v.x *= nrm; v.y *= nrm; v.z *= nrm; v.w *= nrm;
            xd[c0 + j] = v;
        }
    }
    __syncthreads();

    const int g  = tid >> 5;
    const int c4 = tid & 31;

    float4 a0 = make_float4(0.f,0.f,0.f,0.f), a1 = a0, a2 = a0, a3 = a0;
#pragma unroll 4
    for (int k = 0; k < HD; ++k) {
        float4 wv = Ws4[k * 32 + c4];
        float x0 = xs[g * 4 + 0][k];
        float x1 = xs[g * 4 + 1][k];
        float x2 = xs[g * 4 + 2][k];
        float x3 = xs[g * 4 + 3][k];
        a0.x = fmaf(x0, wv.x, a0.x); a0.y = fmaf(x0, wv.y, a0.y);
        a0.z = fmaf(x0, wv.z, a0.z); a0.w = fmaf(x0, wv.w, a0.w);
        a1.x = fmaf(x1, wv.x, a1.x); a1.y = fmaf(x1, wv.y, a1.y);
        a1.z = fmaf(x1, wv.z, a1.z); a1.w = fmaf(x1, wv.w, a1.w);
        a2.x = fmaf(x2, wv.x, a2.x); a2.y = fmaf(x2, wv.y, a2.y);
        a2.z = fmaf(x2, wv.z, a2.z); a2.w = fmaf(x2, wv.w, a2.w);
        a3.x = fmaf(x3, wv.x, a3.x); a3.y = fmaf(x3, wv.y, a3.y);
        a3.z = fmaf(x3, wv.z, a3.z); a3.w = fmaf(x3, wv.w, a3.w);
    }

#pragma unroll
    for (int j = 0; j < 4; ++j) {
        int row = row0 + g * 4 + j;
        if (row >= n) break;
        float4 a = (j == 0) ? a0 : (j == 1) ? a1 : (j == 2) ? a2 : a3;
        __half2 lo = __floats2half2_rn(a.x, a.y);
        __half2 hi = __floats2half2_rn(a.z, a.w);
        uint2 pk;
        pk.x = *(unsigned int*)&lo;
        pk.y = *(unsigned int*)&hi;
        ((uint2*)(h + (size_t)row * HD))[c4] = pk;
    }
}

// ---- fused gather-aggregate + norm + bias + relu: one wave per dst node ----
__global__ __launch_bounds__(256) void aggregate(const __half* __restrict__ h,
                                                 const int* __restrict__ sorted_src,
                                                 const unsigned int* __restrict__ offsets,
                                                 const unsigned int* __restrict__ cnt,
                                                 const float* __restrict__ norm_dst,
                                                 const float* __restrict__ bias,
                                                 float* __restrict__ out, int n) {
    int node = blockIdx.x * 4 + (int)(threadIdx.x >> 6);
    if (node >= n) return;
    int lane = threadIdx.x & 63;

    unsigned int start = offsets[node];
    unsigned int deg   = cnt[node];
    const int* sp = sorted_src + start;
    const __half2* h2 = (const __half2*)h;

    float ax = 0.f, ay = 0.f;
    unsigned int i = 0;
    for (; i + 4 <= deg; i += 4) {
        int s0 = sp[i], s1 = sp[i + 1], s2 = sp[i + 2], s3 = sp[i + 3];
        float2 v0 = __half22float2(h2[(size_t)s0 * 64 + lane]);
        float2 v1 = __half22float2(h2[(size_t)s1 * 64 + lane]);
        float2 v2 = __half22float2(h2[(size_t)s2 * 64 + lane]);
        float2 v3 = __half22float2(h2[(size_t)s3 * 64 + lane]);
        ax += v0.x + v1.x + v2.x + v3.x;
        ay += v0.y + v1.y + v2.y + v3.y;
    }
    for (; i < deg; ++i) {
        int s = sp[i];
        float2 v = __half22float2(h2[(size_t)s * 64 + lane]);
        ax += v.x; ay += v.y;
    }

    float nd = norm_dst[node];
    float2 bb = ((const float2*)bias)[lane];
    float2 o;
    o.x = fmaxf(fmaf(ax, nd, bb.x), 0.f);
    o.y = fmaxf(fmaf(ay, nd, bb.y), 0.f);
    ((float2*)out)[(size_t)node * 64 + lane] = o;
}

extern "C" void kernel_launch(void* const* d_in, const int* in_sizes, int n_in,
                              void* d_out, int out_size, void* d_ws, size_t ws_size,
                              hipStream_t stream) {
    const float* x   = (const float*)d_in[0];
    const float* W1  = (const float*)d_in[1];
    const float* b1  = (const float*)d_in[2];
    const float* W2  = (const float*)d_in[3];
    const float* b2  = (const float*)d_in[4];
    const int*   src = (const int*)d_in[5];
    const int*   dst = (const int*)d_in[6];

    const int N = in_sizes[0] / HD;
    const int E = in_sizes[5];
    float* out = (float*)d_out;

    const int nbA = (N + 255) / 256;          // scan phase-A blocks (<=1024)
    const int nbQ = (E / 4 + 255) / 256;      // quad-edge blocks

    // workspace layout (u32/f32 units)
    float*        norm_src = (float*)d_ws;                  // N
    float*        normd    = norm_src + N;                  // N
    unsigned int* cnt      = (unsigned int*)(normd + N);    // N (total in-deg)
    unsigned int* offsets  = cnt + N;                       // N
    unsigned int* cnt4s    = offsets + N;                   // 4N  (zeroed)
    unsigned int* cnt4d    = cnt4s + 4 * N;                 // 4N  (zeroed)
    unsigned int* cur4     = cnt4d + 4 * N;                 // 4N
    unsigned int* bsum     = cur4 + 4 * N;                  // 1024
    unsigned int* boff     = bsum + 1024;                   // 1024
    int*          sorted   = (int*)(boff + 1024);           // E
    __half*       h        = (__half*)(sorted + E);         // N*HD fp16

    // ---- CSR build (shared by both layers) ----
    hipMemsetAsync(cnt4s, 0, (size_t)8 * N * 4, stream);
    count_deg4<<<nbQ, 256, 0, stream>>>(src, dst, cnt4s, cnt4d, N, E);
    make_norms<<<nbA, 256, 0, stream>>>(cnt4s, cnt4d, norm_src, normd, cnt, N);
    scan_a<<<nbA, 256, 0, stream>>>(cnt, offsets, bsum, N);
    scan_b<<<1, 1024, 0, stream>>>(bsum, boff, nbA);
    scan_c_base<<<nbA, 256, 0, stream>>>(offsets, boff, cnt4d, cur4, N);
    fill_csr4<<<nbQ, 256, 0, stream>>>(src, dst, cur4, sorted, N, E);

    // ---- layer 1 ----
    gemm_norm<<<(N + 31) / 32, 256, 0, stream>>>(x, norm_src, W1, h, N);
    aggregate<<<(N + 3) / 4, 256, 0, stream>>>(h, sorted, offsets, cnt, normd, b1, out, N);

    // ---- layer 2 ----
    gemm_norm<<<(N + 31) / 32, 256, 0, stream>>>(out, norm_src, W2, h, N);
    aggregate<<<(N + 3) / 4, 256, 0, stream>>>(h, sorted, offsets, cnt, normd, b2, out, N);
}

// Round 5
// 389.832 us; speedup vs baseline: 1.3583x; 1.3583x over previous
//
#include <hip/hip_runtime.h>
#include <hip/hip_fp16.h>

#define HD 128      // hidden dim
#define CHUNK 4096  // edges per coarse-sort block
#define MAXNB 512   // max coarse buckets (N/256; N=100K -> 391)

// ---- src out-degree, 4-replica, 4 edges/thread ----
__global__ __launch_bounds__(256) void count_src4(const int* __restrict__ src,
                                                  unsigned int* __restrict__ cnt4s,
                                                  int N, int E) {
    int t = blockIdx.x * 256 + threadIdx.x;
    int e0 = t * 4;
    if (e0 >= E) return;
    if (e0 + 3 < E) {
        int4 s4 = ((const int4*)src)[t];
        atomicAdd(&cnt4s[0 * N + s4.x], 1u);
        atomicAdd(&cnt4s[1 * N + s4.y], 1u);
        atomicAdd(&cnt4s[2 * N + s4.z], 1u);
        atomicAdd(&cnt4s[3 * N + s4.w], 1u);
    } else {
        for (int j = 0; e0 + j < E; ++j)
            atomicAdd(&cnt4s[j * N + src[e0 + j]], 1u);
    }
}

__global__ __launch_bounds__(256) void make_norm_src(const unsigned int* __restrict__ cnt4s,
                                                     float* __restrict__ norm_src, int N) {
    int i = blockIdx.x * 256 + threadIdx.x;
    if (i < N) {
        float od = (float)(cnt4s[i] + cnt4s[N + i] + cnt4s[2 * N + i] + cnt4s[3 * N + i]);
        norm_src[i] = rsqrtf(od > 1.f ? od : 1.f);
    }
}

// ---- coarse histogram: per-chunk LDS hist of dst>>8, bucket-major output ----
__global__ __launch_bounds__(256) void hist_coarse(const int* __restrict__ dst,
                                                   unsigned int* __restrict__ gHist,
                                                   int NB, int NC, int E) {
    __shared__ unsigned int hist[MAXNB];
    for (int b = threadIdx.x; b < NB; b += 256) hist[b] = 0;
    __syncthreads();
    int chunk = blockIdx.x;
    int base = chunk * CHUNK;
    int end = base + CHUNK < E ? base + CHUNK : E;
    for (int e = base + threadIdx.x; e < end; e += 256)
        atomicAdd(&hist[dst[e] >> 8], 1u);
    __syncthreads();
    for (int b = threadIdx.x; b < NB; b += 256)
        gHist[(size_t)b * NC + chunk] = hist[b];
}

// ---- 3-phase exclusive scan (generic length) ----
__global__ __launch_bounds__(256) void scan_a(const unsigned int* __restrict__ cnt,
                                              unsigned int* __restrict__ excl,
                                              unsigned int* __restrict__ bsum, int n) {
    int i = blockIdx.x * 256 + threadIdx.x;
    unsigned int v = (i < n) ? cnt[i] : 0u;
    unsigned int x = v;
#pragma unroll
    for (int d = 1; d < 64; d <<= 1) {
        unsigned int y = __shfl_up(x, d, 64);
        if ((threadIdx.x & 63) >= d) x += y;
    }
    __shared__ unsigned int wsum[4];
    if ((threadIdx.x & 63) == 63) wsum[threadIdx.x >> 6] = x;
    __syncthreads();
    unsigned int woff = 0;
    for (int w = 0; w < (int)(threadIdx.x >> 6); ++w) woff += wsum[w];
    unsigned int incl = x + woff;
    if (i < n) excl[i] = incl - v;
    if (threadIdx.x == 255) bsum[blockIdx.x] = incl;
}

__global__ __launch_bounds__(1024) void scan_b(const unsigned int* __restrict__ bsum,
                                               unsigned int* __restrict__ boff, int nb) {
    int t = threadIdx.x;
    unsigned int v = (t < nb) ? bsum[t] : 0u;
    unsigned int x = v;
#pragma unroll
    for (int d = 1; d < 64; d <<= 1) {
        unsigned int y = __shfl_up(x, d, 64);
        if ((t & 63) >= d) x += y;
    }
    __shared__ unsigned int wsum[16];
    if ((t & 63) == 63) wsum[t >> 6] = x;
    __syncthreads();
    unsigned int woff = 0;
    for (int w = 0; w < (t >> 6); ++w) woff += wsum[w];
    unsigned int incl = x + woff;
    if (t < nb) boff[t] = incl - v;
}

__global__ __launch_bounds__(256) void scan_c(unsigned int* __restrict__ excl,
                                              const unsigned int* __restrict__ boff, int n) {
    int i = blockIdx.x * 256 + threadIdx.x;
    if (i < n) excl[i] += boff[blockIdx.x];
}

// ---- coarse scatter: pack (dst&255)<<24 | src into bucket-contiguous runs ----
__global__ __launch_bounds__(256) void scatter_coarse(const int* __restrict__ src,
                                                      const int* __restrict__ dst,
                                                      const unsigned int* __restrict__ scanA,
                                                      unsigned int* __restrict__ packed,
                                                      int NB, int NC, int E) {
    __shared__ unsigned int curs[MAXNB];
    int chunk = blockIdx.x;
    for (int b = threadIdx.x; b < NB; b += 256)
        curs[b] = scanA[(size_t)b * NC + chunk];
    __syncthreads();
    int base = chunk * CHUNK;
    int end = base + CHUNK < E ? base + CHUNK : E;
    for (int e = base + threadIdx.x; e < end; e += 256) {
        int d = dst[e];
        int s = src[e];
        unsigned int pos = atomicAdd(&curs[d >> 8], 1u);
        packed[pos] = ((unsigned int)(d & 255) << 24) | (unsigned int)s;
    }
}

// ---- fine sort within each bucket + emit offsets/cnt/norm_dst ----
__global__ __launch_bounds__(256) void fine_sort(const unsigned int* __restrict__ packed,
                                                 const unsigned int* __restrict__ scanA,
                                                 int* __restrict__ sorted_src,
                                                 unsigned int* __restrict__ offsets,
                                                 unsigned int* __restrict__ cntg,
                                                 float* __restrict__ normd,
                                                 int NB, int NC, int N, int E) {
    __shared__ unsigned int cnt[256];
    __shared__ unsigned int curs[256];
    __shared__ unsigned int wsum[4];
    int b = blockIdx.x;
    int t = threadIdx.x;
    unsigned int S = scanA[(size_t)b * NC];
    unsigned int T = (b + 1 < NB) ? scanA[(size_t)(b + 1) * NC] : (unsigned int)E;
    cnt[t] = 0;
    __syncthreads();
    for (unsigned int j = S + t; j < T; j += 256)
        atomicAdd(&cnt[packed[j] >> 24], 1u);
    __syncthreads();
    // block exclusive scan over 256 counts
    unsigned int v = cnt[t], x = v;
    int lane = t & 63;
#pragma unroll
    for (int d = 1; d < 64; d <<= 1) {
        unsigned int y = __shfl_up(x, d, 64);
        if (lane >= d) x += y;
    }
    if (lane == 63) wsum[t >> 6] = x;
    __syncthreads();
    unsigned int woff = 0;
    for (int w = 0; w < (t >> 6); ++w) woff += wsum[w];
    unsigned int ex = x - v + woff;
    curs[t] = ex;
    int node = b * 256 + t;
    if (node < N) {
        offsets[node] = S + ex;
        cntg[node] = v;
        float f = (float)v;
        normd[node] = rsqrtf(f > 1.f ? f : 1.f);
    }
    __syncthreads();
    for (unsigned int j = S + t; j < T; j += 256) {
        unsigned int p = packed[j];
        unsigned int pos = S + atomicAdd(&curs[p >> 24], 1u);
        sorted_src[pos] = (int)(p & 0xFFFFFFu);
    }
}

// ---- h = (x * norm_src[:,None]) @ W, fp16 output ----
__global__ __launch_bounds__(256) void gemm_norm(const float* __restrict__ x,
                                                 const float* __restrict__ norm,
                                                 const float* __restrict__ W,
                                                 __half* __restrict__ h, int n) {
    __shared__ float Ws[HD * HD];     // 64 KB
    __shared__ float xs[32][HD];      // 16 KB
    const float4* W4 = (const float4*)W;
    float4* Ws4 = (float4*)Ws;
#pragma unroll
    for (int i = 0; i < 16; ++i)
        Ws4[threadIdx.x + 256 * i] = W4[threadIdx.x + 256 * i];

    const int tid  = threadIdx.x;
    const int row0 = blockIdx.x * 32;

    {
        int r  = tid >> 3;
        int c0 = (tid & 7) * 4;
        int row = row0 + r;
        float nrm = (row < n) ? norm[row] : 0.f;
        const float4* xr = (const float4*)(x + (size_t)row * HD);
        float4* xd = (float4*)xs[r];
#pragma unroll
        for (int j = 0; j < 4; ++j) {
            float4 v = (row < n) ? xr[c0 + j] : make_float4(0.f, 0.f, 0.f, 0.f);
            v.x *= nrm; v.y *= nrm; v.z *= nrm; v.w *= nrm;
            xd[c0 + j] = v;
        }
    }
    __syncthreads();

    const int g  = tid >> 5;
    const int c4 = tid & 31;

    float4 a0 = make_float4(0.f,0.f,0.f,0.f), a1 = a0, a2 = a0, a3 = a0;
#pragma unroll 4
    for (int k = 0; k < HD; ++k) {
        float4 wv = Ws4[k * 32 + c4];
        float x0 = xs[g * 4 + 0][k];
        float x1 = xs[g * 4 + 1][k];
        float x2 = xs[g * 4 + 2][k];
        float x3 = xs[g * 4 + 3][k];
        a0.x = fmaf(x0, wv.x, a0.x); a0.y = fmaf(x0, wv.y, a0.y);
        a0.z = fmaf(x0, wv.z, a0.z); a0.w = fmaf(x0, wv.w, a0.w);
        a1.x = fmaf(x1, wv.x, a1.x); a1.y = fmaf(x1, wv.y, a1.y);
        a1.z = fmaf(x1, wv.z, a1.z); a1.w = fmaf(x1, wv.w, a1.w);
        a2.x = fmaf(x2, wv.x, a2.x); a2.y = fmaf(x2, wv.y, a2.y);
        a2.z = fmaf(x2, wv.z, a2.z); a2.w = fmaf(x2, wv.w, a2.w);
        a3.x = fmaf(x3, wv.x, a3.x); a3.y = fmaf(x3, wv.y, a3.y);
        a3.z = fmaf(x3, wv.z, a3.z); a3.w = fmaf(x3, wv.w, a3.w);
    }

#pragma unroll
    for (int j = 0; j < 4; ++j) {
        int row = row0 + g * 4 + j;
        if (row >= n) break;
        float4 a = (j == 0) ? a0 : (j == 1) ? a1 : (j == 2) ? a2 : a3;
        __half2 lo = __floats2half2_rn(a.x, a.y);
        __half2 hi = __floats2half2_rn(a.z, a.w);
        uint2 pk;
        pk.x = *(unsigned int*)&lo;
        pk.y = *(unsigned int*)&hi;
        ((uint2*)(h + (size_t)row * HD))[c4] = pk;
    }
}

// ---- fused gather-aggregate: wave/node, 4 edges/round x 16B/lane, 2x unroll ----
__global__ __launch_bounds__(256) void aggregate(const __half* __restrict__ h,
                                                 const int* __restrict__ sorted_src,
                                                 const unsigned int* __restrict__ offsets,
                                                 const unsigned int* __restrict__ cnt,
                                                 const float* __restrict__ norm_dst,
                                                 const float* __restrict__ bias,
                                                 float* __restrict__ out, int n) {
    int node = blockIdx.x * 4 + (int)(threadIdx.x >> 6);
    if (node >= n) return;
    int lane = threadIdx.x & 63;
    int g   = lane >> 4;    // edge slot 0..3
    int sub = lane & 15;    // 16B slice of the 256B row

    unsigned int start = offsets[node];
    unsigned int deg   = cnt[node];
    const int* sp = sorted_src + start;
    const uint4* h4 = (const uint4*)h;   // row = 16 x uint4

    float acc[8];
#pragma unroll
    for (int j = 0; j < 8; ++j) acc[j] = 0.f;

#define ACCUM(u)                                                                  \
    { float2 f;                                                                   \
      f = __half22float2(*(const __half2*)&(u).x); acc[0] += f.x; acc[1] += f.y;  \
      f = __half22float2(*(const __half2*)&(u).y); acc[2] += f.x; acc[3] += f.y;  \
      f = __half22float2(*(const __half2*)&(u).z); acc[4] += f.x; acc[5] += f.y;  \
      f = __half22float2(*(const __half2*)&(u).w); acc[6] += f.x; acc[7] += f.y; }

    unsigned int i = 0;
    for (; i + 8 <= deg; i += 8) {
        int s0 = sp[i + g];
        int s1 = sp[i + 4 + g];
        uint4 u0 = h4[(size_t)s0 * 16 + sub];
        uint4 u1 = h4[(size_t)s1 * 16 + sub];
        ACCUM(u0);
        ACCUM(u1);
    }
    for (; i < deg; i += 4) {
        if (i + g < deg) {
            int s = sp[i + g];
            uint4 u = h4[(size_t)s * 16 + sub];
            ACCUM(u);
        }
    }
#undef ACCUM

    // reduce across the 4 edge slots (lanes sub, sub+16, sub+32, sub+48)
#pragma unroll
    for (int j = 0; j < 8; ++j) {
        acc[j] += __shfl_xor(acc[j], 16, 64);
        acc[j] += __shfl_xor(acc[j], 32, 64);
    }

    float nd = norm_dst[node];
    float2 bb = ((const float2*)bias)[sub * 4 + g];
    float2 o;
    o.x = fmaxf(fmaf(acc[g * 2 + 0], nd, bb.x), 0.f);
    o.y = fmaxf(fmaf(acc[g * 2 + 1], nd, bb.y), 0.f);
    ((float2*)out)[(size_t)node * 64 + sub * 4 + g] = o;
}

extern "C" void kernel_launch(void* const* d_in, const int* in_sizes, int n_in,
                              void* d_out, int out_size, void* d_ws, size_t ws_size,
                              hipStream_t stream) {
    const float* x   = (const float*)d_in[0];
    const float* W1  = (const float*)d_in[1];
    const float* b1  = (const float*)d_in[2];
    const float* W2  = (const float*)d_in[3];
    const float* b2  = (const float*)d_in[4];
    const int*   src = (const int*)d_in[5];
    const int*   dst = (const int*)d_in[6];

    const int N = in_sizes[0] / HD;
    const int E = in_sizes[5];
    float* out = (float*)d_out;

    const int NB = (N + 255) / 256;              // coarse buckets (391)
    const int NC = (E + CHUNK - 1) / CHUNK;      // chunks (391)
    const int scanLen = NB * NC;                 // 152881
    const int nbS = (scanLen + 255) / 256;       // 598 <= 1024
    const int nbN = (N + 255) / 256;

    // workspace layout (4B units)
    float*        norm_src = (float*)d_ws;                    // N
    float*        normd    = norm_src + N;                    // N
    unsigned int* cntg     = (unsigned int*)(normd + N);      // N
    unsigned int* offsets  = cntg + N;                        // N
    unsigned int* cnt4s    = offsets + N;                     // 4N (zeroed)
    unsigned int* gHist    = cnt4s + 4 * N;                   // scanLen
    unsigned int* scanA    = gHist + scanLen;                 // scanLen
    unsigned int* bsum     = scanA + scanLen;                 // 1024
    unsigned int* boff     = bsum + 1024;                     // 1024
    unsigned int* packed   = boff + 1024;                     // E
    int*          sorted   = (int*)(packed + E);              // E
    __half*       h        = (__half*)(sorted + E);           // N*HD fp16

    // ---- norms + bucket sort (shared by both layers) ----
    hipMemsetAsync(cnt4s, 0, (size_t)4 * N * 4, stream);
    count_src4<<<(E / 4 + 255) / 256, 256, 0, stream>>>(src, cnt4s, N, E);
    make_norm_src<<<nbN, 256, 0, stream>>>(cnt4s, norm_src, N);
    hist_coarse<<<NC, 256, 0, stream>>>(dst, gHist, NB, NC, E);
    scan_a<<<nbS, 256, 0, stream>>>(gHist, scanA, bsum, scanLen);
    scan_b<<<1, 1024, 0, stream>>>(bsum, boff, nbS);
    scan_c<<<nbS, 256, 0, stream>>>(scanA, boff, scanLen);
    scatter_coarse<<<NC, 256, 0, stream>>>(src, dst, scanA, packed, NB, NC, E);
    fine_sort<<<NB, 256, 0, stream>>>(packed, scanA, sorted, offsets, cntg, normd, NB, NC, N, E);

    // ---- layer 1 ----
    gemm_norm<<<(N + 31) / 32, 256, 0, stream>>>(x, norm_src, W1, h, N);
    aggregate<<<(N + 3) / 4, 256, 0, stream>>>(h, sorted, offsets, cntg, normd, b1, out, N);

    // ---- layer 2 ----
    gemm_norm<<<(N + 31) / 32, 256, 0, stream>>>(out, norm_src, W2, h, N);
    aggregate<<<(N + 3) / 4, 256, 0, stream>>>(h, sorted, offsets, cntg, normd, b2, out, N);
}